// Round 11
// baseline (136.268 us; speedup 1.0000x reference)
//
#include <hip/hip_runtime.h>
#include <hip/hip_bf16.h>

#define BB 8
#define SS 1024
#define IN_DIM 1024
#define NOUT 1024
#define DHEAD 256
#define MTOT (BB*SS)

typedef __bf16 bf16;
typedef __bf16 bf16x8 __attribute__((ext_vector_type(8)));
typedef __bf16 bf16x4 __attribute__((ext_vector_type(4)));
typedef float f32x4 __attribute__((ext_vector_type(4)));
typedef int i32x4 __attribute__((ext_vector_type(4)));

// ws layout (bytes)
#define QK_OFF   0                 // 16 MiB
#define XB_OFF   (16u*1024*1024)   // 16 MiB
#define WB_OFF   (32u*1024*1024)   //  2 MiB
#define RT_OFF   (34u*1024*1024)   //  1 MiB
#define ACC_OFF  (35u*1024*1024)   // 2048 float2 partials

__device__ __forceinline__ void gload_lds16(const void* g, void* l) {
  __builtin_amdgcn_global_load_lds(
      (const __attribute__((address_space(1))) unsigned int*)g,
      (__attribute__((address_space(3))) unsigned int*)l, 16, 0, 0);
}

__global__ void cvt_bf16_kernel(const float* __restrict__ in, bf16* __restrict__ out, int n4) {
  int i = blockIdx.x * blockDim.x + threadIdx.x;
  if (i >= n4) return;
  float4 v = ((const float4*)in)[i];
  bf16x4 o;
  o.x = (bf16)v.x; o.y = (bf16)v.y; o.z = (bf16)v.z; o.w = (bf16)v.w;
  ((bf16x4*)out)[i] = o;
}

__global__ void rope_table_kernel(float2* __restrict__ rt) {
  int i = blockIdx.x * blockDim.x + threadIdx.x;   // S*128 = 131072
  int s = i >> 7, f = i & 127;
  float inv = __expf((float)f * (-2.70805020110221007f / 128.0f)); // 15^(-2f/256)
  float ang = (float)s * inv;
  float c, sn;
  __sincosf(ang, &sn, &c);
  rt[i] = make_float2(c, sn);
}

// C = X(bf16) @ W(bf16)^T + b, fused RoPE, write Q/K bf16 -> ws
// QK layout: [b][h][qk][s][d], qk: 0=Q 1=K
__global__ __launch_bounds__(256) void gemm_rope_kernel(
    const bf16* __restrict__ Xb, const bf16* __restrict__ Wb,
    const float* __restrict__ bias, const float2* __restrict__ rt,
    bf16* __restrict__ QK) {
  __shared__ __align__(16) bf16 lA[128 * 32];
  __shared__ __align__(16) bf16 lB[128 * 32];
  const int tid = threadIdx.x;
  const int lane = tid & 63, w = tid >> 6;
  const int wr = w >> 1, wc = w & 1;
  const int fr = lane & 15, fq = lane >> 4;
  const int m0 = blockIdx.y * 128, n0 = blockIdx.x * 128;
  const int c0 = tid, c1 = tid + 256;

  f32x4 acc[4][4] = {};

  for (int k0 = 0; k0 < IN_DIM; k0 += 32) {
    gload_lds16(Xb + (size_t)(m0 + (c0 >> 2)) * IN_DIM + k0 + (c0 & 3) * 8, &lA[c0 * 8]);
    gload_lds16(Xb + (size_t)(m0 + (c1 >> 2)) * IN_DIM + k0 + (c1 & 3) * 8, &lA[c1 * 8]);
    gload_lds16(Wb + (size_t)(n0 + (c0 >> 2)) * IN_DIM + k0 + (c0 & 3) * 8, &lB[c0 * 8]);
    gload_lds16(Wb + (size_t)(n0 + (c1 >> 2)) * IN_DIM + k0 + (c1 & 3) * 8, &lB[c1 * 8]);
    __syncthreads();
    bf16x8 af[4], bv[4];
#pragma unroll
    for (int i = 0; i < 4; i++) af[i] = *(const bf16x8*)&lA[(wr * 64 + i * 16 + fr) * 32 + fq * 8];
#pragma unroll
    for (int j = 0; j < 4; j++) bv[j] = *(const bf16x8*)&lB[(wc * 64 + j * 16 + fr) * 32 + fq * 8];
#pragma unroll
    for (int i = 0; i < 4; i++)
#pragma unroll
      for (int j = 0; j < 4; j++)
        acc[i][j] = __builtin_amdgcn_mfma_f32_16x16x32_bf16(af[i], bv[j], acc[i][j], 0, 0, 0);
    __syncthreads();
  }

#pragma unroll
  for (int i = 0; i < 4; i++) {
    const int mb = m0 + wr * 64 + i * 16 + fq * 4;
#pragma unroll
    for (int j2 = 0; j2 < 4; j2++) {
      const int n = n0 + wc * 64 + j2 * 16 + fr;
      const float bvn = bias[n];
#pragma unroll
      for (int j = 0; j < 4; j++) {
        float v = acc[i][j2][j] + bvn;
        float p = __shfl_xor(v, 1);
        float rot = (n & 1) ? p : -p;
        const int m_ = mb + j;
        const int s = m_ & (SS - 1);
        const int d = n & (DHEAD - 1);
        float2 cs = rt[s * 128 + (d >> 1)];
        float o = v * cs.x + rot * cs.y;
        const int bidx = m_ >> 10;
        const int h = n >> 9, qk = (n >> 8) & 1;
        QK[(size_t)((bidx * 2 + h) * 2 + qk) * (SS * DHEAD) + s * DHEAD + d] = (bf16)o;
      }
    }
  }
}

// v11: barrier-free streaming logits kernel.
// Q-tile (16 m x 256d x 2h) staged once in padded LDS (+8 -> 2-way banks).
// Each wave streams 16 n-steps of 16 rows: K frags double-buffered in regs
// (distance-1 prefetch, t-dependent loads -> no LICM sink), labels/masks
// distance-2 prefetch, per-step epilogue (softplus + vectorized stores)
// spreads HBM traffic across the whole block. Swapped MFMA (A=K,B=Q):
// lane owns m=fr, n = nstep+4*fq+j. Grid 512, bid&7 = batch -> XCD-local K.
__global__ __launch_bounds__(256, 2) void logits_loss_kernel(
    const bf16* __restrict__ QK, const int* __restrict__ labels,
    const int* __restrict__ masks, float* __restrict__ out,
    float2* __restrict__ part) {
  __shared__ __align__(16) bf16 lQ[2][16][264];   // [head][row][d + 8 pad]
  const int tid = threadIdx.x;
  const int lane = tid & 63, w = tid >> 6;
  const int fr = lane & 15, fq = lane >> 4;

  const int bid = blockIdx.x;        // 0..511
  const int b = bid & 7;             // batch == XCD slot
  const int m0 = (bid >> 3) * 16;    // m-tile (16 rows) within batch
  const int nw = w * 256;            // wave's n-range (16 steps of 16)

  const size_t HS = (size_t)SS * DHEAD;
  const bf16* Qh[2] = {QK + (size_t)(b * 4 + 0) * HS, QK + (size_t)(b * 4 + 2) * HS};
  const bf16* Kh[2] = {QK + (size_t)(b * 4 + 1) * HS, QK + (size_t)(b * 4 + 3) * HS};

  // ---- stage Q once: 1024 chunks of 8 bf16; thread t -> chunks t+256*i
#pragma unroll
  for (int i = 0; i < 4; i++) {
    const int c = tid + 256 * i;
    const int h = c >> 9, rem = c & 511, row = rem >> 5, kc = rem & 31;
    bf16x8 v = *(const bf16x8*)(Qh[h] + (size_t)(m0 + row) * DHEAD + kc * 8);
    *(bf16x8*)&lQ[h][row][kc * 8] = v;
  }
  __syncthreads();

  // per-lane bases
  const bf16* k0p = Kh[0] + (size_t)(nw + fr) * DHEAD + fq * 8;
  const bf16* k1p = Kh[1] + (size_t)(nw + fr) * DHEAD + fq * 8;
  const size_t lmBase = ((size_t)(b * SS + m0 + fr)) * SS + nw + 4 * fq;

  bf16x8 ka[2][16];       // [buf][h*8+kk] K fragments, double-buffered
  i32x4 lab[2], msk[2];   // distance-2 label/mask prefetch

#define LOADK(buf, t_)                                                          \
  do {                                                                          \
    _Pragma("unroll") for (int kk = 0; kk < 8; kk++) {                          \
      ka[buf][kk]     = *(const bf16x8*)(k0p + (size_t)(t_) * 16 * DHEAD + kk * 32); \
      ka[buf][8 + kk] = *(const bf16x8*)(k1p + (size_t)(t_) * 16 * DHEAD + kk * 32); \
    }                                                                           \
  } while (0)

  LOADK(0, 0);
  lab[0] = *(const i32x4*)(labels + lmBase);
  msk[0] = *(const i32x4*)(masks + lmBase);
  lab[1] = *(const i32x4*)(labels + lmBase + 16);
  msk[1] = *(const i32x4*)(masks + lmBase + 16);

  float s_sum = 0.f, s_cnt = 0.f;

#pragma unroll
  for (int t = 0; t < 16; ++t) {
    const int cur = t & 1;
    if (t < 15) LOADK(cur ^ 1, t + 1);   // next K tile in flight during this step

    f32x4 a0 = {}, a1 = {};
#pragma unroll
    for (int kk = 0; kk < 8; kk++) {
      bf16x8 bq = *(const bf16x8*)&lQ[0][fr][kk * 32 + fq * 8];
      a0 = __builtin_amdgcn_mfma_f32_16x16x32_bf16(ka[cur][kk], bq, a0, 0, 0, 0);
    }
#pragma unroll
    for (int kk = 0; kk < 8; kk++) {
      bf16x8 bq = *(const bf16x8*)&lQ[1][fr][kk * 32 + fq * 8];
      a1 = __builtin_amdgcn_mfma_f32_16x16x32_bf16(ka[cur][8 + kk], bq, a1, 0, 0, 0);
    }

    // ---- per-step epilogue: lane owns row m0+fr, 4 consecutive n
    const size_t p = lmBase + (size_t)t * 16;
    float* op = out + 1 + 2 * p;
    op[0] = a0[0];
    *(float2*)(op + 1) = make_float2(a1[0], a0[1]);
    float4 v4; v4.x = a1[1]; v4.y = a0[2]; v4.z = a1[2]; v4.w = a0[3];
    *(float4*)(op + 3) = v4;
    op[7] = a1[3];

    const i32x4 L = lab[cur], M = msk[cur];
#pragma unroll
    for (int j = 0; j < 4; j++) {
      float l0 = a0[j], l1 = a1[j];
      float mk = (float)M[j];                 // PAIR_POS_WEIGHT==1 -> wl = mask
      float zz = l1 - l0;
      float z = L[j] ? -zz : zz;              // l_other - l_label
      float mz = fmaxf(z, 0.f);
      s_sum += mk * (mz + __logf(__expf(-mz) + __expf(z - mz)));  // stable softplus
      s_cnt += mk;
    }
    if (t < 14) {                              // distance-2 reload into freed slot
      lab[cur] = *(const i32x4*)(labels + lmBase + (size_t)(t + 2) * 16);
      msk[cur] = *(const i32x4*)(masks + lmBase + (size_t)(t + 2) * 16);
    }
  }

#pragma unroll
  for (int off = 32; off; off >>= 1) {
    s_sum += __shfl_down(s_sum, off);
    s_cnt += __shfl_down(s_cnt, off);
  }
  if (lane == 0) part[bid * 4 + w] = make_float2(s_sum, s_cnt);
}

__global__ __launch_bounds__(1024) void finalize_kernel(const float2* __restrict__ part,
                                                        float* __restrict__ out) {
  __shared__ float red[32];
  const int tid = threadIdx.x;
  const int lane = tid & 63, w = tid >> 6;
  float s = 0.f, c = 0.f;
#pragma unroll
  for (int i = 0; i < 2; i++) {
    float2 v = part[tid + i * 1024];
    s += v.x; c += v.y;
  }
#pragma unroll
  for (int off = 32; off; off >>= 1) {
    s += __shfl_down(s, off);
    c += __shfl_down(c, off);
  }
  if (lane == 0) { red[w] = s; red[16 + w] = c; }
  __syncthreads();
  if (tid == 0) {
    float ts = 0.f, tc = 0.f;
#pragma unroll
    for (int i = 0; i < 16; i++) { ts += red[i]; tc += red[16 + i]; }
    out[0] = ts / tc;
  }
}

extern "C" void kernel_launch(void* const* d_in, const int* in_sizes, int n_in,
                              void* d_out, int out_size, void* d_ws, size_t ws_size,
                              hipStream_t stream) {
  const float* X = (const float*)d_in[0];
  const int* labels = (const int*)d_in[1];
  const int* masks = (const int*)d_in[2];
  const float* W = (const float*)d_in[3];
  const float* bias = (const float*)d_in[4];
  float* out = (float*)d_out;
  char* ws = (char*)d_ws;

  bf16* QK = (bf16*)(ws + QK_OFF);
  bf16* Xb = (bf16*)(ws + XB_OFF);
  bf16* Wb = (bf16*)(ws + WB_OFF);
  float2* rt = (float2*)(ws + RT_OFF);
  float2* part = (float2*)(ws + ACC_OFF);

  cvt_bf16_kernel<<<(MTOT * IN_DIM / 4 + 255) / 256, 256, 0, stream>>>(X, Xb, MTOT * IN_DIM / 4);
  cvt_bf16_kernel<<<(NOUT * IN_DIM / 4 + 255) / 256, 256, 0, stream>>>(W, Wb, NOUT * IN_DIM / 4);
  rope_table_kernel<<<(SS * 128) / 256, 256, 0, stream>>>(rt);
  gemm_rope_kernel<<<dim3(NOUT / 128, MTOT / 128), 256, 0, stream>>>(Xb, Wb, bias, rt, QK);
  logits_loss_kernel<<<512, 256, 0, stream>>>(QK, labels, masks, out, part);
  finalize_kernel<<<1, 1024, 0, stream>>>(part, out);
}

// Round 12
// 99.521 us; speedup vs baseline: 1.3692x; 1.3692x over previous
//
#include <hip/hip_runtime.h>
#include <hip/hip_bf16.h>

#define BB 8
#define SS 1024
#define IN_DIM 1024
#define NOUT 1024
#define DHEAD 256
#define MTOT (BB*SS)

typedef __bf16 bf16;
typedef __bf16 bf16x8 __attribute__((ext_vector_type(8)));
typedef __bf16 bf16x4 __attribute__((ext_vector_type(4)));
typedef float f32x4 __attribute__((ext_vector_type(4)));
typedef float f32x16 __attribute__((ext_vector_type(16)));
typedef int i32x4 __attribute__((ext_vector_type(4)));

// ws layout (bytes)
#define QK_OFF   0                 // 16 MiB
#define XB_OFF   (16u*1024*1024)   // 16 MiB
#define WB_OFF   (32u*1024*1024)   //  2 MiB
#define RT_OFF   (34u*1024*1024)   //  1 MiB
#define ACC_OFF  (35u*1024*1024)   // 8192 float2 partials

__device__ __forceinline__ void gload_lds16(const void* g, void* l) {
  __builtin_amdgcn_global_load_lds(
      (const __attribute__((address_space(1))) unsigned int*)g,
      (__attribute__((address_space(3))) unsigned int*)l, 16, 0, 0);
}

__global__ void cvt_bf16_kernel(const float* __restrict__ in, bf16* __restrict__ out, int n4) {
  int i = blockIdx.x * blockDim.x + threadIdx.x;
  if (i >= n4) return;
  float4 v = ((const float4*)in)[i];
  bf16x4 o;
  o.x = (bf16)v.x; o.y = (bf16)v.y; o.z = (bf16)v.z; o.w = (bf16)v.w;
  ((bf16x4*)out)[i] = o;
}

__global__ void rope_table_kernel(float2* __restrict__ rt) {
  int i = blockIdx.x * blockDim.x + threadIdx.x;   // S*128 = 131072
  int s = i >> 7, f = i & 127;
  float inv = __expf((float)f * (-2.70805020110221007f / 128.0f)); // 15^(-2f/256)
  float ang = (float)s * inv;
  float c, sn;
  __sincosf(ang, &sn, &c);
  rt[i] = make_float2(c, sn);
}

// C = X(bf16) @ W(bf16)^T + b, fused RoPE, write Q/K bf16 -> ws
// QK layout: [b][h][qk][s][d], qk: 0=Q 1=K
__global__ __launch_bounds__(256) void gemm_rope_kernel(
    const bf16* __restrict__ Xb, const bf16* __restrict__ Wb,
    const float* __restrict__ bias, const float2* __restrict__ rt,
    bf16* __restrict__ QK) {
  __shared__ __align__(16) bf16 lA[128 * 32];
  __shared__ __align__(16) bf16 lB[128 * 32];
  const int tid = threadIdx.x;
  const int lane = tid & 63, w = tid >> 6;
  const int wr = w >> 1, wc = w & 1;
  const int fr = lane & 15, fq = lane >> 4;
  const int m0 = blockIdx.y * 128, n0 = blockIdx.x * 128;
  const int c0 = tid, c1 = tid + 256;

  f32x4 acc[4][4] = {};

  for (int k0 = 0; k0 < IN_DIM; k0 += 32) {
    gload_lds16(Xb + (size_t)(m0 + (c0 >> 2)) * IN_DIM + k0 + (c0 & 3) * 8, &lA[c0 * 8]);
    gload_lds16(Xb + (size_t)(m0 + (c1 >> 2)) * IN_DIM + k0 + (c1 & 3) * 8, &lA[c1 * 8]);
    gload_lds16(Wb + (size_t)(n0 + (c0 >> 2)) * IN_DIM + k0 + (c0 & 3) * 8, &lB[c0 * 8]);
    gload_lds16(Wb + (size_t)(n0 + (c1 >> 2)) * IN_DIM + k0 + (c1 & 3) * 8, &lB[c1 * 8]);
    __syncthreads();
    bf16x8 af[4], bv[4];
#pragma unroll
    for (int i = 0; i < 4; i++) af[i] = *(const bf16x8*)&lA[(wr * 64 + i * 16 + fr) * 32 + fq * 8];
#pragma unroll
    for (int j = 0; j < 4; j++) bv[j] = *(const bf16x8*)&lB[(wc * 64 + j * 16 + fr) * 32 + fq * 8];
#pragma unroll
    for (int i = 0; i < 4; i++)
#pragma unroll
      for (int j = 0; j < 4; j++)
        acc[i][j] = __builtin_amdgcn_mfma_f32_16x16x32_bf16(af[i], bv[j], acc[i][j], 0, 0, 0);
    __syncthreads();
  }

#pragma unroll
  for (int i = 0; i < 4; i++) {
    const int mb = m0 + wr * 64 + i * 16 + fq * 4;
#pragma unroll
    for (int j2 = 0; j2 < 4; j2++) {
      const int n = n0 + wc * 64 + j2 * 16 + fr;
      const float bvn = bias[n];
#pragma unroll
      for (int j = 0; j < 4; j++) {
        float v = acc[i][j2][j] + bvn;
        float p = __shfl_xor(v, 1);
        float rot = (n & 1) ? p : -p;
        const int m_ = mb + j;
        const int s = m_ & (SS - 1);
        const int d = n & (DHEAD - 1);
        float2 cs = rt[s * 128 + (d >> 1)];
        float o = v * cs.x + rot * cs.y;
        const int bidx = m_ >> 10;
        const int h = n >> 9, qk = (n >> 8) & 1;
        QK[(size_t)((bidx * 2 + h) * 2 + qk) * (SS * DHEAD) + s * DHEAD + d] = (bf16)o;
      }
    }
  }
}

// v12: stage-once, barrier-free compute.
// Block 64m x 64n x 2h; LDS = full operand set: lQ/lK each 128 rows x 512 B
// (= 64 KB each, 128 KiB total). Staging: 1 gload_lds = 2 complete rows
// (64 lanes x 16B contiguous) -> 4-8 cache lines/instr; 3-bit XOR chunk
// swizzle via permuted source within the row (coalescing preserved).
// Compute: fully unrolled K=256 loop, mfma_32x32x16 (1 MFMA covers a wave's
// whole 32x32 tile per k16; 2 reads/MFMA; no barriers). Swapped operands
// (A=K,B=Q): lane owns m=lane&31, n-runs of 4 -> int4 labels + wide stores.
__global__ __launch_bounds__(256, 1) void logits_loss_kernel(
    const bf16* __restrict__ QK, const int* __restrict__ labels,
    const int* __restrict__ masks, float* __restrict__ out,
    float2* __restrict__ part) {
  __shared__ __align__(16) bf16 lQ[128 * 256];   // 64 KiB: rows h*64+m_local
  __shared__ __align__(16) bf16 lK[128 * 256];   // 64 KiB: rows h*64+n_local
  const int tid = threadIdx.x;
  const int lane = tid & 63, w = tid >> 6;
  const int wr = w >> 1, wc = w & 1;
  const int l31 = lane & 31, hi = lane >> 5;

  const int bid = blockIdx.x;     // 0..2047
  const int b = bid & 7;          // batch == XCD slot
  const int r = bid >> 3;         // 0..255
  const int m0 = (r & 15) * 64;
  const int n0 = (r >> 4) * 64;

  const size_t HS = (size_t)SS * DHEAD;
  const bf16* Qh[2] = {QK + (size_t)(b * 4 + 0) * HS, QK + (size_t)(b * 4 + 2) * HS};
  const bf16* Kh[2] = {QK + (size_t)(b * 4 + 1) * HS, QK + (size_t)(b * 4 + 3) * HS};

  // ---- stage once: wave w stages rows [w*32, w*32+32) of both lQ and lK.
  // One instr = 2 rows (lane hi-bit selects row, lane&31 selects 16B chunk).
  // Source chunk pre-swizzled: physical slot p holds logical chunk p^(row&7).
#pragma unroll
  for (int i = 0; i < 16; i++) {
    const int r2 = w * 32 + 2 * i;          // even row base
    const int rr = r2 + hi;                 // this lane's row (0..127)
    const int gc = (l31 ^ (rr & 7)) * 8;    // swizzled source chunk (elems)
    gload_lds16(Qh[rr >> 6] + (size_t)(m0 + (rr & 63)) * DHEAD + gc, &lQ[r2 * 256]);
    gload_lds16(Kh[rr >> 6] + (size_t)(n0 + (rr & 63)) * DHEAD + gc, &lK[r2 * 256]);
  }

  // ---- label/mask prefetch (completes under the same barrier)
  const int m = m0 + wr * 32 + l31;                  // this lane's m row
  const int nb = n0 + wc * 32 + 4 * hi;              // n-run bases: nb + 8g
  const size_t pb = (size_t)(b * SS + m) * SS + nb;
  i32x4 lab[4], msk[4];
#pragma unroll
  for (int g = 0; g < 4; g++) {
    lab[g] = *(const i32x4*)(labels + pb + 8 * g);
    msk[g] = *(const i32x4*)(masks + pb + 8 * g);
  }

  __syncthreads();   // drains vmcnt -> staging + prefetch complete
#pragma unroll
  for (int g = 0; g < 4; g++) {
    asm volatile("" : "+v"(lab[g]));
    asm volatile("" : "+v"(msk[g]));
  }

  // ---- barrier-free K=256 compute, 32x32x16 MFMA
  const int RQ = wr * 32 + l31, RK = wc * 32 + l31;
  const int sQ = RQ & 7, sK = RK & 7;
  const bf16* q0 = &lQ[RQ * 256];
  const bf16* q1 = &lQ[(64 + RQ) * 256];
  const bf16* k0 = &lK[RK * 256];
  const bf16* k1 = &lK[(64 + RK) * 256];

  f32x16 acc0 = {}, acc1 = {};
#pragma unroll
  for (int t = 0; t < 16; t++) {
    const int c = 2 * t + hi;                 // logical 16B chunk (k = c*8..)
    const int cQ = (c ^ sQ) * 8, cK = (c ^ sK) * 8;
    acc0 = __builtin_amdgcn_mfma_f32_32x32x16_bf16(
        *(const bf16x8*)(k0 + cK), *(const bf16x8*)(q0 + cQ), acc0, 0, 0, 0);
    acc1 = __builtin_amdgcn_mfma_f32_32x32x16_bf16(
        *(const bf16x8*)(k1 + cK), *(const bf16x8*)(q1 + cQ), acc1, 0, 0, 0);
  }

  // ---- epilogue: lane owns m (col=lane&31), n = nb + 8g + j (reg = g*4+j)
  float s_sum = 0.f, s_cnt = 0.f;
#pragma unroll
  for (int g = 0; g < 4; g++) {
    const size_t p = pb + 8 * g;
    float l0v[4] = {acc0[g * 4 + 0], acc0[g * 4 + 1], acc0[g * 4 + 2], acc0[g * 4 + 3]};
    float l1v[4] = {acc1[g * 4 + 0], acc1[g * 4 + 1], acc1[g * 4 + 2], acc1[g * 4 + 3]};
    float* op = out + 1 + 2 * p;
    op[0] = l0v[0];
    *(float2*)(op + 1) = make_float2(l1v[0], l0v[1]);
    float4 v4; v4.x = l1v[1]; v4.y = l0v[2]; v4.z = l1v[2]; v4.w = l0v[3];
    *(float4*)(op + 3) = v4;
    op[7] = l1v[3];
#pragma unroll
    for (int j = 0; j < 4; j++) {
      float mk = (float)msk[g][j];                   // PAIR_POS_WEIGHT==1 -> wl = mask
      float zz = l1v[j] - l0v[j];
      float z = lab[g][j] ? -zz : zz;                // l_other - l_label
      float mz = fmaxf(z, 0.f);
      s_sum += mk * (mz + __logf(__expf(-mz) + __expf(z - mz)));  // stable softplus
      s_cnt += mk;
    }
  }

#pragma unroll
  for (int off = 32; off; off >>= 1) {
    s_sum += __shfl_down(s_sum, off);
    s_cnt += __shfl_down(s_cnt, off);
  }
  if (lane == 0) part[bid * 4 + w] = make_float2(s_sum, s_cnt);
}

__global__ __launch_bounds__(1024) void finalize_kernel(const float2* __restrict__ part,
                                                        float* __restrict__ out) {
  __shared__ float red[32];
  const int tid = threadIdx.x;
  const int lane = tid & 63, w = tid >> 6;
  float s = 0.f, c = 0.f;
#pragma unroll
  for (int i = 0; i < 8; i++) {
    float2 v = part[tid + i * 1024];
    s += v.x; c += v.y;
  }
#pragma unroll
  for (int off = 32; off; off >>= 1) {
    s += __shfl_down(s, off);
    c += __shfl_down(c, off);
  }
  if (lane == 0) { red[w] = s; red[16 + w] = c; }
  __syncthreads();
  if (tid == 0) {
    float ts = 0.f, tc = 0.f;
#pragma unroll
    for (int i = 0; i < 16; i++) { ts += red[i]; tc += red[16 + i]; }
    out[0] = ts / tc;
  }
}

extern "C" void kernel_launch(void* const* d_in, const int* in_sizes, int n_in,
                              void* d_out, int out_size, void* d_ws, size_t ws_size,
                              hipStream_t stream) {
  const float* X = (const float*)d_in[0];
  const int* labels = (const int*)d_in[1];
  const int* masks = (const int*)d_in[2];
  const float* W = (const float*)d_in[3];
  const float* bias = (const float*)d_in[4];
  float* out = (float*)d_out;
  char* ws = (char*)d_ws;

  bf16* QK = (bf16*)(ws + QK_OFF);
  bf16* Xb = (bf16*)(ws + XB_OFF);
  bf16* Wb = (bf16*)(ws + WB_OFF);
  float2* rt = (float2*)(ws + RT_OFF);
  float2* part = (float2*)(ws + ACC_OFF);

  cvt_bf16_kernel<<<(MTOT * IN_DIM / 4 + 255) / 256, 256, 0, stream>>>(X, Xb, MTOT * IN_DIM / 4);
  cvt_bf16_kernel<<<(NOUT * IN_DIM / 4 + 255) / 256, 256, 0, stream>>>(W, Wb, NOUT * IN_DIM / 4);
  rope_table_kernel<<<(SS * 128) / 256, 256, 0, stream>>>(rt);
  gemm_rope_kernel<<<dim3(NOUT / 128, MTOT / 128), 256, 0, stream>>>(Xb, Wb, bias, rt, QK);
  logits_loss_kernel<<<2048, 256, 0, stream>>>(QK, labels, masks, out, part);
  finalize_kernel<<<1, 1024, 0, stream>>>(part, out);
}